// Round 11
// baseline (616.058 us; speedup 1.0000x reference)
//
#include <hip/hip_runtime.h>
#include <math.h>

#define AT 24
#define ATP 32
#define HD 128
#define GD 50
#define NT 3
#define EPM 552
#define EPAD 576
#define CUTOFF 10.0f
#define NK 1024        // table knots
#define NKR (NK+4)     // + zero sentinel rows (self-edges -> row NK+1)
#define NPREP 427      // 36 transpose + 4 out_w1 + 384 table slabs + 3 sentinel

#define KP_W 136       // padded K stride (bf16) for K=128
#define XFP 132        // xf fp32 row stride

#define SZ_BIG (128*KP_W)
#define WS_LIN1(t) ((t)*SZ_BIG)
#define WS_LIN2(t) ((3+(t))*SZ_BIG)
#define WS_LIN(t)  ((6+(t))*SZ_BIG)
#define WS_OW1     (9*SZ_BIG)
#define WS_TAB     (9*SZ_BIG + 64*KP_W)   // [NT][NKR][256] u16: per col-pair (T0,T1,D0,D1)

typedef __attribute__((ext_vector_type(8))) short short8;
typedef __attribute__((ext_vector_type(4))) float f32x4;

__device__ __forceinline__ unsigned short f2bf(float x) {
    unsigned int u = __float_as_uint(x);
    return (unsigned short)((u + 0x7fffu + ((u >> 16) & 1u)) >> 16);
}
__device__ __forceinline__ float sspf(float x) {
    return fmaxf(x, 0.0f) + __logf(1.0f + __expf(-fabsf(x))) - 0.69314718055994531f;
}

// async global->LDS; bytes multiple of 1024; 512 threads
__device__ __forceinline__ void g2l_async(const void* g, void* l, int bytes, int tid) {
    int w = tid >> 6, lane = tid & 63;
    const char* gc = (const char*)g + lane * 16;
    char* lc = (char*)l + lane * 16;
    for (int ofs = w * 1024; ofs < bytes; ofs += 8192) {
        __builtin_amdgcn_global_load_lds(
            (const __attribute__((address_space(1))) unsigned int*)(gc + ofs),
            (__attribute__((address_space(3))) unsigned int*)(lc + ofs), 16, 0, 0);
    }
}

__device__ __forceinline__ f32x4 mfma16(short8 a, short8 b, f32x4 c) {
    return __builtin_amdgcn_mfma_f32_16x16x32_bf16(a, b, c, 0, 0, 0);
}

template<int NKT>
__device__ __forceinline__ void gemm2(const unsigned short* A, const unsigned short* B,
                                      int q, f32x4* acc)
{
#pragma unroll
    for (int kt = 0; kt < NKT; ++kt) {
        short8 a  = *(const short8*)(A + kt * 32 + q * 8);
        short8 b0 = *(const short8*)(B + kt * 32 + q * 8);
        short8 b1 = *(const short8*)(B + 64 * KP_W + kt * 32 + q * 8);
        acc[0] = mfma16(a, b0, acc[0]);
        acc[1] = mfma16(a, b1, acc[1]);
    }
}

// ---- prep: one unit per block (verified in R10) ----
__global__ __launch_bounds__(512) void prep(
    const float* __restrict__ lin1_w, const float* __restrict__ lin2_w,
    const float* __restrict__ lin_w,  const float* __restrict__ out_w1,
    const float* __restrict__ mlp_w1, const float* __restrict__ mlp_b1,
    const float* __restrict__ mlp_w2, const float* __restrict__ mlp_b2,
    unsigned short* __restrict__ ws)
{
    const int u = blockIdx.x, tid = threadIdx.x;
    if (u < 36) {          // transpose one 32-row slice of a 128x128 weight
        int mat = u >> 2, slice = u & 3;
        int grp = mat / 3, t = mat - grp * 3;
        const float* bases[3] = {lin1_w, lin2_w, lin_w};
        const float* src = bases[grp] + t * HD * HD;
        unsigned short* dst = ws + (grp * 3 + t) * SZ_BIG;
        int n0 = slice * 32;
        int nn = tid & 31, kk = tid >> 5;   // kk in [0,16)
        for (int k = kk; k < KP_W; k += 16) {
            float v = (k < HD) ? src[k * HD + n0 + nn] : 0.f;
            dst[(n0 + nn) * KP_W + k] = f2bf(v);
        }
    } else if (u < 40) {   // out_w1: 16-row slices
        int n0 = (u - 36) * 16;
        unsigned short* dst = ws + WS_OW1;
        int nn = tid & 31, kk = tid >> 5;
        if (nn < 16) {
            for (int k = kk; k < KP_W; k += 16) {
                float v = (k < HD) ? out_w1[k * 64 + n0 + nn] : 0.f;
                dst[(n0 + nn) * KP_W + k] = f2bf(v);
            }
        }
    } else if (u < 424) {  // table slab: (t, 8 knots)
        __shared__ float ea12[12 * 52];
        __shared__ float hid12[12 * 132];
        int u2 = u - 40;
        int t = u2 >> 7, k0 = (u2 & 127) << 3;
        const float h = CUTOFF / (NK - 1);
        const float STEP = CUTOFF / (GD - 1);
        const float COEFF = -0.5f / (STEP * STEP);
        for (int i = tid; i < 12 * GD; i += 512) {
            int row = i / GD, g = i - row * GD;
            int k = min(k0 + (row / 3) * 2 + (row % 3), NK - 1);
            float d = (float)k * h - (float)g * STEP;
            ea12[row * 52 + g] = __expf(COEFF * d * d);
        }
        __syncthreads();
        int j = tid & 127, kh = tid >> 7;      // kh in [0,4): knots k0+2kh+{0,1}, +1 row for delta
        float pre[3], acc3[3], Tv[3];
        float bb1 = mlp_b1[t * HD + j];
#pragma unroll
        for (int rr = 0; rr < 3; ++rr) pre[rr] = bb1;
        for (int g = 0; g < GD; ++g) {
            float wv = mlp_w1[t * GD * HD + g * HD + j];
#pragma unroll
            for (int rr = 0; rr < 3; ++rr)
                pre[rr] = fmaf(ea12[(kh * 3 + rr) * 52 + g], wv, pre[rr]);
        }
#pragma unroll
        for (int rr = 0; rr < 3; ++rr) hid12[(kh * 3 + rr) * 132 + j] = sspf(pre[rr]);
        __syncthreads();
        float bb2 = mlp_b2[t * HD + j];
#pragma unroll
        for (int rr = 0; rr < 3; ++rr) acc3[rr] = bb2;
        for (int uu = 0; uu < HD; ++uu) {
            float wv = mlp_w2[t * HD * HD + uu * HD + j];
#pragma unroll
            for (int rr = 0; rr < 3; ++rr)
                acc3[rr] = fmaf(hid12[(kh * 3 + rr) * 132 + uu], wv, acc3[rr]);
        }
#pragma unroll
        for (int rr = 0; rr < 3; ++rr) {
            int k = min(k0 + kh * 2 + rr, NK - 1);
            float r = (float)k * h;
            Tv[rr] = acc3[rr] * 0.5f * (__cosf(r * 0.31415926535897931f) + 1.0f);
        }
        unsigned short* tb = ws + WS_TAB + (size_t)t * NKR * 256;
#pragma unroll
        for (int rr = 0; rr < 2; ++rr) {
            int k = k0 + kh * 2 + rr;
            int ofs = k * 256 + (j >> 1) * 4 + (j & 1);
            tb[ofs]     = f2bf(Tv[rr]);
            tb[ofs + 2] = f2bf(Tv[rr + 1] - Tv[rr]);
        }
    } else {               // zero sentinel rows NK..NK+3 for t = u-424
        int t = u - 424;
        unsigned int* tb = (unsigned int*)(ws + WS_TAB + (size_t)t * NKR * 256 + NK * 256);
        tb[tid] = 0u;
    }
}

// ---- main: R7 structure (LDS-staged weights) + R10 uint4 edge-agg ----
extern "C" __global__ __launch_bounds__(512, 4)
void schnet_tab(const int* __restrict__ z, const float* __restrict__ pos,
                const float* __restrict__ emb,
                const float* __restrict__ lin2_b, const float* __restrict__ lin_b,
                const float* __restrict__ out_b1, const float* __restrict__ out_w2,
                const float* __restrict__ out_b2,
                const unsigned short* __restrict__ ws,
                float* __restrict__ out)
{
    __shared__ __align__(16) unsigned char uni_s[ATP * XFP * 4];  // xf fp32 / tmp bf16 union
    __shared__ __align__(16) unsigned short hb_s[ATP * KP_W];
    __shared__ __align__(16) unsigned short aggb_s[ATP * KP_W];
    __shared__ __align__(16) unsigned short wbuf_s[SZ_BIG];
    __shared__ float u_s[EPAD];
    __shared__ float pos_s[AT * 4];
    __shared__ float lb2_s[NT * HD], lb_s[NT * HD];
    __shared__ float ob1_s[64], ow2_s[64];
    __shared__ float red_s;
    float* xf_s = (float*)uni_s;
    unsigned short* tmp_s = (unsigned short*)uni_s;

    const int tid = threadIdx.x, m = blockIdx.x, base = m * AT;
    const int w = tid >> 6, lane = tid & 63, q = lane >> 4, lm = lane & 15;
    const int rn = w & 1, cn = w >> 1;

    g2l_async(ws + WS_LIN1(0), wbuf_s, SZ_BIG * 2, tid);

    // ---- init
    if (tid < AT * 3) pos_s[(tid / 3) * 4 + tid % 3] = pos[base * 3 + tid];
    if (tid < NT * HD) { lb2_s[tid] = lin2_b[tid]; lb_s[tid] = lin_b[tid]; }
    else if (tid < NT * HD + 64) ob1_s[tid - NT * HD] = out_b1[tid - NT * HD];
    else if (tid < NT * HD + 128) ow2_s[tid - NT * HD - 64] = out_w2[tid - NT * HD - 64];
    if (tid == 0) red_s = 0.f;
    float hreg[2][4];
#pragma unroll
    for (int c = 0; c < 2; ++c)
#pragma unroll
        for (int i = 0; i < 4; ++i) {
            int row = rn * 16 + q * 4 + i, col = cn * 16 + c * 64 + lm;
            float v = (row < AT) ? emb[z[base + row] * HD + col] : 0.f;
            hreg[c][i] = v;
            hb_s[row * KP_W + col] = f2bf(v);
        }
    for (int i = tid; i < 8 * HD; i += 512)
        aggb_s[(24 + (i >> 7)) * KP_W + (i & 127)] = 0;   // pad rows clean
    __syncthreads();
    const float INVH = (float)(NK - 1) / CUTOFF;
    for (int e = tid; e < EPAD; e += 512) {
        float u = (float)(NK + 1);   // sentinel -> zero table row (self-edges e>=EPM)
        if (e < EPM) {
            int s = e / 23, ix = e % 23;
            int d = ix + (ix >= s ? 1 : 0);
            float dx = pos_s[s * 4 + 0] - pos_s[d * 4 + 0];
            float dy = pos_s[s * 4 + 1] - pos_s[d * 4 + 1];
            float dz = pos_s[s * 4 + 2] - pos_s[d * 4 + 2];
            u = sqrtf(dx * dx + dy * dy + dz * dz) * INVH;
        }
        u_s[e] = u;
    }

    for (int t = 0; t < NT; ++t) {
        __syncthreads();   // B1: wbuf=lin1 ready, hb + u_s ready, tmp readers done
        {   // xf = h @ lin1 (fp32)
            f32x4 acc[2] = {};
            gemm2<4>(&hb_s[(rn * 16 + lm) * KP_W], &wbuf_s[(cn * 16 + lm) * KP_W], q, acc);
#pragma unroll
            for (int c = 0; c < 2; ++c) {
                int col = cn * 16 + c * 64 + lm;
#pragma unroll
                for (int i = 0; i < 4; ++i)
                    xf_s[(rn * 16 + q * 4 + i) * XFP + col] = acc[c][i];
            }
        }
        __syncthreads();   // B2: xf visible, wbuf readers done
        g2l_async(ws + WS_LIN2(t), wbuf_s, SZ_BIG * 2, tid);
        short8 lf[2][4];   // lin(t) B-fragments in registers
        {
            const unsigned short* lwp = ws + WS_LIN(t);
#pragma unroll
            for (int c = 0; c < 2; ++c)
#pragma unroll
                for (int kt = 0; kt < 4; ++kt)
                    lf[c][kt] = *(const short8*)(lwp + (cn * 16 + c * 64 + lm) * KP_W + kt * 32 + q * 8);
        }
        // ---- edge aggregation: half-wave hv = s parity; lane covers 4 cols (uint4)
        {
            const unsigned short* Tt = ws + WS_TAB + (size_t)t * NKR * 256;
            const int hv = lane >> 5, p = lane & 31;
            float ac[3][4] = {};
#pragma unroll
            for (int sp = 0; sp < AT; sp += 2) {
                int s = sp + hv;
                float4 xf4 = *(const float4*)&xf_s[s * XFP + p * 4];
#pragma unroll
                for (int r = 0; r < 3; ++r) {
                    int a = w + 8 * r;
                    int e = (s == a) ? (EPM + s) : (s * 23 + a - (a > s ? 1 : 0));
                    float u = u_s[e];
                    int idx = (int)u;
                    float f = u - (float)idx;
                    uint4 pk = *(const uint4*)(Tt + (size_t)idx * 256 + p * 8);
                    float t0 = __uint_as_float(pk.x << 16);
                    float t1 = __uint_as_float(pk.x & 0xFFFF0000u);
                    float d0 = __uint_as_float(pk.y << 16);
                    float d1 = __uint_as_float(pk.y & 0xFFFF0000u);
                    float t2 = __uint_as_float(pk.z << 16);
                    float t3 = __uint_as_float(pk.z & 0xFFFF0000u);
                    float d2 = __uint_as_float(pk.w << 16);
                    float d3 = __uint_as_float(pk.w & 0xFFFF0000u);
                    ac[r][0] = fmaf(fmaf(f, d0, t0), xf4.x, ac[r][0]);
                    ac[r][1] = fmaf(fmaf(f, d1, t1), xf4.y, ac[r][1]);
                    ac[r][2] = fmaf(fmaf(f, d2, t2), xf4.z, ac[r][2]);
                    ac[r][3] = fmaf(fmaf(f, d3, t3), xf4.w, ac[r][3]);
                }
            }
#pragma unroll
            for (int r = 0; r < 3; ++r) {
                int a = w + 8 * r;
#pragma unroll
                for (int c = 0; c < 4; ++c) ac[r][c] += __shfl_xor(ac[r][c], 32);
                if (hv == 0) {
                    uint2 pk2;
                    pk2.x = ((unsigned)f2bf(ac[r][1]) << 16) | (unsigned)f2bf(ac[r][0]);
                    pk2.y = ((unsigned)f2bf(ac[r][3]) << 16) | (unsigned)f2bf(ac[r][2]);
                    *(uint2*)&aggb_s[a * KP_W + p * 4] = pk2;
                }
            }
        }
        __syncthreads();   // B3: aggb visible, wbuf=lin2 ready
        {   // tmp = ssp(agg @ lin2 + b)
            f32x4 acc[2] = {};
            gemm2<4>(&aggb_s[(rn * 16 + lm) * KP_W], &wbuf_s[(cn * 16 + lm) * KP_W], q, acc);
#pragma unroll
            for (int c = 0; c < 2; ++c) {
                int col = cn * 16 + c * 64 + lm;
                float bb = lb2_s[t * HD + col];
#pragma unroll
                for (int i = 0; i < 4; ++i)
                    tmp_s[(rn * 16 + q * 4 + i) * KP_W + col] = f2bf(sspf(acc[c][i] + bb));
            }
        }
        __syncthreads();   // B4: tmp visible, wbuf readers done
        if (t < NT - 1) g2l_async(ws + WS_LIN1(t + 1), wbuf_s, SZ_BIG * 2, tid);
        else            g2l_async(ws + WS_OW1, wbuf_s, 64 * KP_W * 2, tid);
        {   // h += tmp @ lin + b (lin in registers)
            f32x4 acc[2] = {};
            const unsigned short* A = &tmp_s[(rn * 16 + lm) * KP_W];
#pragma unroll
            for (int kt = 0; kt < 4; ++kt) {
                short8 a = *(const short8*)(A + kt * 32 + q * 8);
                acc[0] = mfma16(a, lf[0][kt], acc[0]);
                acc[1] = mfma16(a, lf[1][kt], acc[1]);
            }
#pragma unroll
            for (int c = 0; c < 2; ++c) {
                int col = cn * 16 + c * 64 + lm;
                float bb = lb_s[t * HD + col];
#pragma unroll
                for (int i = 0; i < 4; ++i) {
                    int row = rn * 16 + q * 4 + i;
                    float nh = hreg[c][i] + acc[c][i] + bb;
                    hreg[c][i] = nh;
                    hb_s[row * KP_W + col] = f2bf(nh);
                }
            }
        }
    }

    // ---- output head: sum_a ( ssp(h@ow1+b1) @ ow2 ) + 24*b2
    __syncthreads();   // hb ready, wbuf=ow1 ready
    {
        int rt = w & 1, co = w >> 1;   // C: 32x64 = 2x4 tiles
        int j = co * 16 + lm;
        f32x4 acc = {};
        const unsigned short* A = &hb_s[(rt * 16 + lm) * KP_W];
        const unsigned short* B = &wbuf_s[j * KP_W];
#pragma unroll
        for (int kt = 0; kt < 4; ++kt)
            acc = mfma16(*(const short8*)(A + kt * 32 + q * 8),
                         *(const short8*)(B + kt * 32 + q * 8), acc);
        float sum = 0.f;
        float bb = ob1_s[j], wo = ow2_s[j];
#pragma unroll
        for (int i = 0; i < 4; ++i) {
            int row = rt * 16 + q * 4 + i;
            if (row < AT) sum += sspf(acc[i] + bb) * wo;
        }
        for (int off = 32; off > 0; off >>= 1) sum += __shfl_down(sum, off);
        if (lane == 0) atomicAdd(&red_s, sum);
    }
    __syncthreads();
    if (tid == 0) out[m] = red_s + (float)AT * out_b2[0];
}

extern "C" void kernel_launch(void* const* d_in, const int* in_sizes, int n_in,
                              void* d_out, int out_size, void* d_ws, size_t ws_size,
                              hipStream_t stream) {
    const int*   z    = (const int*)  d_in[0];
    const float* pos  = (const float*)d_in[1];
    const float* emb  = (const float*)d_in[4];
    const float* mw1  = (const float*)d_in[5];
    const float* mb1  = (const float*)d_in[6];
    const float* mw2  = (const float*)d_in[7];
    const float* mb2  = (const float*)d_in[8];
    const float* l1w  = (const float*)d_in[9];
    const float* l2w  = (const float*)d_in[10];
    const float* l2b  = (const float*)d_in[11];
    const float* lw   = (const float*)d_in[12];
    const float* lb   = (const float*)d_in[13];
    const float* ow1  = (const float*)d_in[14];
    const float* ob1  = (const float*)d_in[15];
    const float* ow2  = (const float*)d_in[16];
    const float* ob2  = (const float*)d_in[17];

    unsigned short* ws = (unsigned short*)d_ws;

    prep<<<dim3(NPREP), dim3(512), 0, stream>>>(l1w, l2w, lw, ow1, mw1, mb1, mw2, mb2, ws);
    schnet_tab<<<dim3(1024), dim3(512), 0, stream>>>(
        z, pos, emb, l2b, lb, ob1, ow2, ob2, ws, (float*)d_out);
}

// Round 12
// 332.591 us; speedup vs baseline: 1.8523x; 1.8523x over previous
//
#include <hip/hip_runtime.h>
#include <math.h>

#define AT 24
#define ATP 32
#define HD 128
#define GD 50
#define NT 3
#define EPM 552
#define CUTOFF 10.0f
#define NK 1024        // table knots
#define NKR (NK+4)     // rows incl sentinel padding (unused by main; matches prep layout)
#define NPREP 427      // 36 transpose + 4 out_w1 + 384 table slabs + 3 sentinel

#define KP_W 136       // padded K stride (bf16) for K=128
#define XFP 132        // xf fp32 row stride

#define SZ_BIG (128*KP_W)
#define WS_LIN1(t) ((t)*SZ_BIG)
#define WS_LIN2(t) ((3+(t))*SZ_BIG)
#define WS_LIN(t)  ((6+(t))*SZ_BIG)
#define WS_OW1     (9*SZ_BIG)
#define WS_TAB     (9*SZ_BIG + 64*KP_W)   // [NT][NKR][256] u16: per col-pair (T0,T1,D0,D1)

typedef __attribute__((ext_vector_type(8))) short short8;
typedef __attribute__((ext_vector_type(4))) float f32x4;

__device__ __forceinline__ unsigned short f2bf(float x) {
    unsigned int u = __float_as_uint(x);
    return (unsigned short)((u + 0x7fffu + ((u >> 16) & 1u)) >> 16);
}
__device__ __forceinline__ float sspf(float x) {
    return fmaxf(x, 0.0f) + __logf(1.0f + __expf(-fabsf(x))) - 0.69314718055994531f;
}
__device__ __forceinline__ f32x4 mfma16(short8 a, short8 b, f32x4 c) {
    return __builtin_amdgcn_mfma_f32_16x16x32_bf16(a, b, c, 0, 0, 0);
}

// A from LDS, B from global (direct MFMA operands; R10-proven)
template<int NKT>
__device__ __forceinline__ void gemm2(const unsigned short* A, const unsigned short* B,
                                      int q, f32x4* acc)
{
#pragma unroll
    for (int kt = 0; kt < NKT; ++kt) {
        short8 a  = *(const short8*)(A + kt * 32 + q * 8);
        short8 b0 = *(const short8*)(B + kt * 32 + q * 8);
        short8 b1 = *(const short8*)(B + 64 * KP_W + kt * 32 + q * 8);
        acc[0] = mfma16(a, b0, acc[0]);
        acc[1] = mfma16(a, b1, acc[1]);
    }
}

// ---- prep: one unit per block (byte-identical to R11's, proven) ----
__global__ __launch_bounds__(512) void prep(
    const float* __restrict__ lin1_w, const float* __restrict__ lin2_w,
    const float* __restrict__ lin_w,  const float* __restrict__ out_w1,
    const float* __restrict__ mlp_w1, const float* __restrict__ mlp_b1,
    const float* __restrict__ mlp_w2, const float* __restrict__ mlp_b2,
    unsigned short* __restrict__ ws)
{
    const int u = blockIdx.x, tid = threadIdx.x;
    if (u < 36) {
        int mat = u >> 2, slice = u & 3;
        int grp = mat / 3, t = mat - grp * 3;
        const float* bases[3] = {lin1_w, lin2_w, lin_w};
        const float* src = bases[grp] + t * HD * HD;
        unsigned short* dst = ws + (grp * 3 + t) * SZ_BIG;
        int n0 = slice * 32;
        int nn = tid & 31, kk = tid >> 5;
        for (int k = kk; k < KP_W; k += 16) {
            float v = (k < HD) ? src[k * HD + n0 + nn] : 0.f;
            dst[(n0 + nn) * KP_W + k] = f2bf(v);
        }
    } else if (u < 40) {
        int n0 = (u - 36) * 16;
        unsigned short* dst = ws + WS_OW1;
        int nn = tid & 31, kk = tid >> 5;
        if (nn < 16) {
            for (int k = kk; k < KP_W; k += 16) {
                float v = (k < HD) ? out_w1[k * 64 + n0 + nn] : 0.f;
                dst[(n0 + nn) * KP_W + k] = f2bf(v);
            }
        }
    } else if (u < 424) {
        __shared__ float ea12[12 * 52];
        __shared__ float hid12[12 * 132];
        int u2 = u - 40;
        int t = u2 >> 7, k0 = (u2 & 127) << 3;
        const float h = CUTOFF / (NK - 1);
        const float STEP = CUTOFF / (GD - 1);
        const float COEFF = -0.5f / (STEP * STEP);
        for (int i = tid; i < 12 * GD; i += 512) {
            int row = i / GD, g = i - row * GD;
            int k = min(k0 + (row / 3) * 2 + (row % 3), NK - 1);
            float d = (float)k * h - (float)g * STEP;
            ea12[row * 52 + g] = __expf(COEFF * d * d);
        }
        __syncthreads();
        int j = tid & 127, kh = tid >> 7;
        float pre[3], acc3[3], Tv[3];
        float bb1 = mlp_b1[t * HD + j];
#pragma unroll
        for (int rr = 0; rr < 3; ++rr) pre[rr] = bb1;
        for (int g = 0; g < GD; ++g) {
            float wv = mlp_w1[t * GD * HD + g * HD + j];
#pragma unroll
            for (int rr = 0; rr < 3; ++rr)
                pre[rr] = fmaf(ea12[(kh * 3 + rr) * 52 + g], wv, pre[rr]);
        }
#pragma unroll
        for (int rr = 0; rr < 3; ++rr) hid12[(kh * 3 + rr) * 132 + j] = sspf(pre[rr]);
        __syncthreads();
        float bb2 = mlp_b2[t * HD + j];
#pragma unroll
        for (int rr = 0; rr < 3; ++rr) acc3[rr] = bb2;
        for (int uu = 0; uu < HD; ++uu) {
            float wv = mlp_w2[t * HD * HD + uu * HD + j];
#pragma unroll
            for (int rr = 0; rr < 3; ++rr)
                acc3[rr] = fmaf(hid12[(kh * 3 + rr) * 132 + uu], wv, acc3[rr]);
        }
#pragma unroll
        for (int rr = 0; rr < 3; ++rr) {
            int k = min(k0 + kh * 2 + rr, NK - 1);
            float r = (float)k * h;
            Tv[rr] = acc3[rr] * 0.5f * (__cosf(r * 0.31415926535897931f) + 1.0f);
        }
        unsigned short* tb = ws + WS_TAB + (size_t)t * NKR * 256;
#pragma unroll
        for (int rr = 0; rr < 2; ++rr) {
            int k = k0 + kh * 2 + rr;
            int ofs = k * 256 + (j >> 1) * 4 + (j & 1);
            tb[ofs]     = f2bf(Tv[rr]);
            tb[ofs + 2] = f2bf(Tv[rr + 1] - Tv[rr]);
        }
    } else {
        int t = u - 424;
        unsigned int* tb = (unsigned int*)(ws + WS_TAB + (size_t)t * NKR * 256 + NK * 256);
        tb[tid] = 0u;
    }
}

// ---- main: R7 dataflow (scalar uint2 edge-agg) + global-B GEMMs, no wbuf ----
// LDS ~39.5 KB; __launch_bounds__(512,6) -> VGPR cap 85, 3 blocks/CU.
extern "C" __global__ __launch_bounds__(512, 6)
void schnet_tab(const int* __restrict__ z, const float* __restrict__ pos,
                const float* __restrict__ emb,
                const float* __restrict__ lin2_b, const float* __restrict__ lin_b,
                const float* __restrict__ out_b1, const float* __restrict__ out_w2,
                const float* __restrict__ out_b2,
                const unsigned short* __restrict__ ws,
                float* __restrict__ out)
{
    __shared__ __align__(16) unsigned char uni_s[ATP * XFP * 4];  // xf fp32 / tmp bf16 union
    __shared__ __align__(16) unsigned short hb_s[ATP * KP_W];
    __shared__ __align__(16) unsigned short aggb_s[ATP * KP_W];
    __shared__ float u_s[EPM];
    __shared__ float pos_s[AT * 4];
    __shared__ float lb2_s[NT * HD], lb_s[NT * HD];
    __shared__ float ob1_s[64], ow2_s[64];
    __shared__ float red_s;
    float* xf_s = (float*)uni_s;
    unsigned short* tmp_s = (unsigned short*)uni_s;

    const int tid = threadIdx.x, m = blockIdx.x, base = m * AT;
    const int w = tid >> 6, lane = tid & 63, q = lane >> 4, lm = lane & 15;
    const int rn = w & 1, cn = w >> 1;   // node GEMMs: rows rn*16, cols cn*16 + c*64

    // ---- init
    if (tid < AT * 3) pos_s[(tid / 3) * 4 + tid % 3] = pos[base * 3 + tid];
    if (tid < NT * HD) { lb2_s[tid] = lin2_b[tid]; lb_s[tid] = lin_b[tid]; }
    else if (tid < NT * HD + 64) ob1_s[tid - NT * HD] = out_b1[tid - NT * HD];
    else if (tid < NT * HD + 128) ow2_s[tid - NT * HD - 64] = out_w2[tid - NT * HD - 64];
    if (tid == 0) red_s = 0.f;
    float hreg[2][4];
#pragma unroll
    for (int c = 0; c < 2; ++c)
#pragma unroll
        for (int i = 0; i < 4; ++i) {
            int row = rn * 16 + q * 4 + i, col = cn * 16 + c * 64 + lm;
            float v = (row < AT) ? emb[z[base + row] * HD + col] : 0.f;
            hreg[c][i] = v;
            hb_s[row * KP_W + col] = f2bf(v);
        }
    for (int i = tid; i < 8 * HD; i += 512)
        aggb_s[(24 + (i >> 7)) * KP_W + (i & 127)] = 0;   // pad rows clean
    __syncthreads();
    const float INVH = (float)(NK - 1) / CUTOFF;
    for (int e = tid; e < EPM; e += 512) {
        int s = e / 23, ix = e % 23;
        int d = ix + (ix >= s ? 1 : 0);
        float dx = pos_s[s * 4 + 0] - pos_s[d * 4 + 0];
        float dy = pos_s[s * 4 + 1] - pos_s[d * 4 + 1];
        float dz = pos_s[s * 4 + 2] - pos_s[d * 4 + 2];
        u_s[e] = sqrtf(dx * dx + dy * dy + dz * dz) * INVH;
    }

    for (int t = 0; t < NT; ++t) {
        __syncthreads();   // B1: hb + u_s ready; prev tmp readers done
        {   // xf = h @ lin1 (fp32), B from global
            f32x4 acc[2] = {};
            gemm2<4>(&hb_s[(rn * 16 + lm) * KP_W],
                     ws + WS_LIN1(t) + (cn * 16 + lm) * KP_W, q, acc);
#pragma unroll
            for (int c = 0; c < 2; ++c) {
                int col = cn * 16 + c * 64 + lm;
#pragma unroll
                for (int i = 0; i < 4; ++i)
                    xf_s[(rn * 16 + q * 4 + i) * XFP + col] = acc[c][i];
            }
        }
        __syncthreads();   // B2: xf visible
        // ---- edge aggregation (R7-proven scalar form; item = (a = w+8r, col-pair = lane))
        {
            const unsigned short* Tt = ws + WS_TAB + (size_t)t * NKR * 256 + lane * 4;
            float agx[3] = {0.f, 0.f, 0.f}, agy[3] = {0.f, 0.f, 0.f};
            for (int s = 0; s < AT; ++s) {
                float2 xf2 = *(const float2*)&xf_s[s * XFP + lane * 2];
#pragma unroll
                for (int r = 0; r < 3; ++r) {
                    int a = w + 8 * r;
                    if (s == a) continue;
                    int e = s * 23 + a - (a > s ? 1 : 0);
                    float u = u_s[e];
                    int idx = (int)u;
                    float f = u - (float)idx;
                    uint2 pk = *(const uint2*)(Tt + idx * 256);
                    float t0 = __uint_as_float(pk.x << 16);
                    float t1 = __uint_as_float(pk.x & 0xFFFF0000u);
                    float d0 = __uint_as_float(pk.y << 16);
                    float d1 = __uint_as_float(pk.y & 0xFFFF0000u);
                    agx[r] = fmaf(fmaf(f, d0, t0), xf2.x, agx[r]);
                    agy[r] = fmaf(fmaf(f, d1, t1), xf2.y, agy[r]);
                }
            }
#pragma unroll
            for (int r = 0; r < 3; ++r) {
                int a = w + 8 * r;
                unsigned pk = ((unsigned)f2bf(agy[r]) << 16) | (unsigned)f2bf(agx[r]);
                *(unsigned*)&aggb_s[a * KP_W + lane * 2] = pk;
            }
        }
        __syncthreads();   // B3: aggb visible; xf readers done (tmp reuses region)
        {   // tmp = ssp(agg @ lin2 + b), B from global
            f32x4 acc[2] = {};
            gemm2<4>(&aggb_s[(rn * 16 + lm) * KP_W],
                     ws + WS_LIN2(t) + (cn * 16 + lm) * KP_W, q, acc);
#pragma unroll
            for (int c = 0; c < 2; ++c) {
                int col = cn * 16 + c * 64 + lm;
                float bb = lb2_s[t * HD + col];
#pragma unroll
                for (int i = 0; i < 4; ++i)
                    tmp_s[(rn * 16 + q * 4 + i) * KP_W + col] = f2bf(sspf(acc[c][i] + bb));
            }
        }
        __syncthreads();   // B4: tmp visible
        {   // h += tmp @ lin + b, B from global
            f32x4 acc[2] = {};
            gemm2<4>(&tmp_s[(rn * 16 + lm) * KP_W],
                     ws + WS_LIN(t) + (cn * 16 + lm) * KP_W, q, acc);
#pragma unroll
            for (int c = 0; c < 2; ++c) {
                int col = cn * 16 + c * 64 + lm;
                float bb = lb_s[t * HD + col];
#pragma unroll
                for (int i = 0; i < 4; ++i) {
                    int row = rn * 16 + q * 4 + i;
                    float nh = hreg[c][i] + acc[c][i] + bb;
                    hreg[c][i] = nh;
                    hb_s[row * KP_W + col] = f2bf(nh);
                }
            }
        }
    }

    // ---- output head: sum_a ( ssp(h@ow1+b1) @ ow2 ) + 24*b2
    __syncthreads();   // hb ready
    {
        int rt = w & 1, co = w >> 1;   // C: 32x64 = 2x4 tiles
        int j = co * 16 + lm;
        f32x4 acc = {};
        const unsigned short* A = &hb_s[(rt * 16 + lm) * KP_W];
        const unsigned short* B = ws + WS_OW1 + j * KP_W;
#pragma unroll
        for (int kt = 0; kt < 4; ++kt)
            acc = mfma16(*(const short8*)(A + kt * 32 + q * 8),
                         *(const short8*)(B + kt * 32 + q * 8), acc);
        float sum = 0.f;
        float bb = ob1_s[j], wo = ow2_s[j];
#pragma unroll
        for (int i = 0; i < 4; ++i) {
            int row = rt * 16 + q * 4 + i;
            if (row < AT) sum += sspf(acc[i] + bb) * wo;
        }
        for (int off = 32; off > 0; off >>= 1) sum += __shfl_down(sum, off);
        if (lane == 0) atomicAdd(&red_s, sum);
    }
    __syncthreads();
    if (tid == 0) out[m] = red_s + (float)AT * out_b2[0];
}

extern "C" void kernel_launch(void* const* d_in, const int* in_sizes, int n_in,
                              void* d_out, int out_size, void* d_ws, size_t ws_size,
                              hipStream_t stream) {
    const int*   z    = (const int*)  d_in[0];
    const float* pos  = (const float*)d_in[1];
    const float* emb  = (const float*)d_in[4];
    const float* mw1  = (const float*)d_in[5];
    const float* mb1  = (const float*)d_in[6];
    const float* mw2  = (const float*)d_in[7];
    const float* mb2  = (const float*)d_in[8];
    const float* l1w  = (const float*)d_in[9];
    const float* l2w  = (const float*)d_in[10];
    const float* l2b  = (const float*)d_in[11];
    const float* lw   = (const float*)d_in[12];
    const float* lb   = (const float*)d_in[13];
    const float* ow1  = (const float*)d_in[14];
    const float* ob1  = (const float*)d_in[15];
    const float* ow2  = (const float*)d_in[16];
    const float* ob2  = (const float*)d_in[17];

    unsigned short* ws = (unsigned short*)d_ws;

    prep<<<dim3(NPREP), dim3(512), 0, stream>>>(l1w, l2w, lw, ow1, mw1, mb1, mw2, mb2, ws);
    schnet_tab<<<dim3(1024), dim3(512), 0, stream>>>(
        z, pos, emb, l2b, lb, ob1, ow2, ob2, ws, (float*)d_out);
}